// Round 1
// baseline (131.078 us; speedup 1.0000x reference)
//
#include <hip/hip_runtime.h>
#include <hip/hip_bf16.h>

#define NN 8192
#define INF 128
#define OUTF 64
#define EMB 32
#define LOG2E 1.4426950408889634f
#define ISPLIT 16
#define ICH (NN / ISPLIT)

typedef __attribute__((ext_vector_type(8))) short bf16x8;
typedef __attribute__((ext_vector_type(4))) float f32x4;

// workspace offsets (bytes)
#define OFF_HT   0u         // bf16 hT[64][8192]            : 1048576
#define OFF_ES   1048576u   // f32 esL[8192]  (= e_src*log2e): 32768
#define OFF_ED   1081344u   // f32 edL[8192]  (= e_dst*log2e): 32768
#define OFF_Q    1114112u   // f32 qL[8192]   (= beta*ii*log2e): 32768
#define OFF_MAX  1146880u   // f32 mx[2] = {max esL, max qL} : 256
#define OFF_SP   1147136u   // f32 Spart[16][8192]           : 524288
#define OFF_CC   1671424u   // f32 cc[8192]                  : 32768
#define OFF_PART 1704192u   // f32 part[JS][8192][64]

// ---------------- Kernel 1: h = input@W, hT(bf16), esL, edL, qL ----------------
__global__ __launch_bounds__(256) void k1_h(
    const float* __restrict__ input, const float* __restrict__ Wm,
    const float* __restrict__ av, const float* __restrict__ embeds,
    const float* __restrict__ intw, const float* __restrict__ betap,
    __hip_bfloat16* __restrict__ hT, float* __restrict__ esL,
    float* __restrict__ edL, float* __restrict__ qL)
{
    const int wid  = threadIdx.x >> 6;
    const int lane = threadIdx.x & 63;
    const int i = blockIdx.x * 4 + wid;

    const float a1 = av[lane];
    const float a2 = av[64 + lane];
    const float* xrow = input + (size_t)i * INF;

    float acc = 0.f;
#pragma unroll
    for (int k = 0; k < INF; k += 4) {
        float4 xv = *(const float4*)(xrow + k);
        acc = fmaf(xv.x, Wm[(k + 0) * OUTF + lane], acc);
        acc = fmaf(xv.y, Wm[(k + 1) * OUTF + lane], acc);
        acc = fmaf(xv.z, Wm[(k + 2) * OUTF + lane], acc);
        acc = fmaf(xv.w, Wm[(k + 3) * OUTF + lane], acc);
    }
    // transposed bf16 copy of h for MFMA B-operand
    hT[(size_t)lane * NN + i] = __float2bfloat16(acc);

    // e_src / e_dst via full-wave reductions
    float v1 = acc * a1;
    float v2 = acc * a2;
#pragma unroll
    for (int o = 32; o > 0; o >>= 1) {
        v1 += __shfl_xor(v1, o);
        v2 += __shfl_xor(v2, o);
    }
    // intent ii (jj and intent_b cancel in the column softmax)
    float p = 0.f;
    if (lane < EMB) p = embeds[(size_t)i * EMB + lane] * intw[lane];
#pragma unroll
    for (int o = 16; o > 0; o >>= 1) p += __shfl_xor(p, o);

    if (lane == 0) {
        esL[i] = v1 * LOG2E;
        edL[i] = v2 * LOG2E;
        qL[i]  = betap[0] * p * LOG2E;
    }
}

// ---------------- Kernel 1b: global maxes of esL, qL ----------------
__global__ __launch_bounds__(256) void k1b_max(
    const float* __restrict__ esL, const float* __restrict__ qL,
    float* __restrict__ mx)
{
    float me = -1e30f, mq = -1e30f;
    for (int i = threadIdx.x; i < NN; i += 256) {
        me = fmaxf(me, esL[i]);
        mq = fmaxf(mq, qL[i]);
    }
#pragma unroll
    for (int o = 32; o > 0; o >>= 1) {
        me = fmaxf(me, __shfl_xor(me, o));
        mq = fmaxf(mq, __shfl_xor(mq, o));
    }
    __shared__ float sm[8];
    int wid = threadIdx.x >> 6, lane = threadIdx.x & 63;
    if (lane == 0) { sm[wid] = me; sm[4 + wid] = mq; }
    __syncthreads();
    if (threadIdx.x == 0) {
        mx[0] = fmaxf(fmaxf(sm[0], sm[1]), fmaxf(sm[2], sm[3]));
        mx[1] = fmaxf(fmaxf(sm[4], sm[5]), fmaxf(sm[6], sm[7]));
    }
}

// ---------------- Kernel 2: partial column sums S_j (exp2 domain) ----------------
__global__ __launch_bounds__(256) void k2_colsum(
    const float* __restrict__ esL, const float* __restrict__ edL,
    const float* __restrict__ qL, const float* __restrict__ mx,
    float* __restrict__ Spart)
{
    __shared__ float ls[ICH];
    __shared__ float lq[ICH];
    const int j = blockIdx.x * 256 + threadIdx.x;
    const int i0 = blockIdx.y * ICH;
    for (int r = threadIdx.x; r < ICH; r += 256) {
        ls[r] = esL[i0 + r];
        lq[r] = qL[i0 + r];
    }
    __syncthreads();

    const float edj = edL[j];
    const float tm = mx[0] + edj;
    const float Mj = fmaxf(tm, 0.2f * tm) + mx[1];   // upper bound of column max

    float s = 0.f;
#pragma unroll 8
    for (int r = 0; r < ICH; ++r) {
        float t = ls[r] + edj;
        float d = lq[r] - Mj;
        float x = fmaxf(t + d, fmaf(t, 0.2f, d));    // lrelu(t)+d
        s += __builtin_amdgcn_exp2f(x);
    }
    Spart[(size_t)blockIdx.y * NN + j] = s;
}

// ---------------- Kernel 3: cc_j = M_j + log2(S_j) ----------------
__global__ __launch_bounds__(256) void k3_cc(
    const float* __restrict__ edL, const float* __restrict__ mx,
    const float* __restrict__ Spart, float* __restrict__ cc)
{
    const int j = blockIdx.x * 256 + threadIdx.x;
    float s = 0.f;
#pragma unroll
    for (int k = 0; k < ISPLIT; ++k) s += Spart[(size_t)k * NN + j];
    const float tm = mx[0] + edL[j];
    const float Mj = fmaxf(tm, 0.2f * tm) + mx[1];
    cc[j] = Mj + __builtin_amdgcn_logf(s);
}

__device__ __forceinline__ float wexp(float esi, float qi, float ed, float c) {
    float t = esi + ed;
    float d = qi - c;
    float x = fmaxf(t + d, fmaf(t, 0.2f, d));
    return __builtin_amdgcn_exp2f(x);
}

// ---------------- Kernel 4: h_prime partial = attention @ h (MFMA bf16) ----------------
__global__ __launch_bounds__(256) void k4_mm(
    const float* __restrict__ esL, const float* __restrict__ edL,
    const float* __restrict__ qL, const float* __restrict__ cc,
    const short* __restrict__ hTu, float* __restrict__ part, int jchunk)
{
    const int wid  = threadIdx.x >> 6;
    const int lane = threadIdx.x & 63;
    const int r = lane & 15;       // A row within 16-tile; also B/D col
    const int g = lane >> 4;       // k-group
    const int ibase = blockIdx.x * 64 + wid * 16;
    const int i = ibase + r;

    const float esi = esL[i];
    const float qi  = qL[i];

    const int jb = blockIdx.y * jchunk;
    const int je = jb + jchunk;

    f32x4 acc0 = {0.f, 0.f, 0.f, 0.f};
    f32x4 acc1 = {0.f, 0.f, 0.f, 0.f};
    f32x4 acc2 = {0.f, 0.f, 0.f, 0.f};
    f32x4 acc3 = {0.f, 0.f, 0.f, 0.f};

    for (int j0 = jb; j0 < je; j0 += 32) {
        const int jj = j0 + g * 8;
        const float4 ed0 = *(const float4*)(edL + jj);
        const float4 ed1 = *(const float4*)(edL + jj + 4);
        const float4 cc0 = *(const float4*)(cc + jj);
        const float4 cc1 = *(const float4*)(cc + jj + 4);

        float e0 = wexp(esi, qi, ed0.x, cc0.x);
        float e1 = wexp(esi, qi, ed0.y, cc0.y);
        float e2 = wexp(esi, qi, ed0.z, cc0.z);
        float e3 = wexp(esi, qi, ed0.w, cc0.w);
        float e4 = wexp(esi, qi, ed1.x, cc1.x);
        float e5 = wexp(esi, qi, ed1.y, cc1.y);
        float e6 = wexp(esi, qi, ed1.z, cc1.z);
        float e7 = wexp(esi, qi, ed1.w, cc1.w);

        union { bf16x8 v; unsigned u[4]; } A;
        asm("v_cvt_pk_bf16_f32 %0, %1, %2" : "=v"(A.u[0]) : "v"(e0), "v"(e1));
        asm("v_cvt_pk_bf16_f32 %0, %1, %2" : "=v"(A.u[1]) : "v"(e2), "v"(e3));
        asm("v_cvt_pk_bf16_f32 %0, %1, %2" : "=v"(A.u[2]) : "v"(e4), "v"(e5));
        asm("v_cvt_pk_bf16_f32 %0, %1, %2" : "=v"(A.u[3]) : "v"(e6), "v"(e7));

        const bf16x8 b0 = *(const bf16x8*)(hTu + (size_t)(0  + r) * NN + jj);
        const bf16x8 b1 = *(const bf16x8*)(hTu + (size_t)(16 + r) * NN + jj);
        const bf16x8 b2 = *(const bf16x8*)(hTu + (size_t)(32 + r) * NN + jj);
        const bf16x8 b3 = *(const bf16x8*)(hTu + (size_t)(48 + r) * NN + jj);

        acc0 = __builtin_amdgcn_mfma_f32_16x16x32_bf16(A.v, b0, acc0, 0, 0, 0);
        acc1 = __builtin_amdgcn_mfma_f32_16x16x32_bf16(A.v, b1, acc1, 0, 0, 0);
        acc2 = __builtin_amdgcn_mfma_f32_16x16x32_bf16(A.v, b2, acc2, 0, 0, 0);
        acc3 = __builtin_amdgcn_mfma_f32_16x16x32_bf16(A.v, b3, acc3, 0, 0, 0);
    }

    float* pout = part + (size_t)blockIdx.y * (NN * OUTF);
#pragma unroll
    for (int m = 0; m < 4; ++m) {
        const int row = ibase + g * 4 + m;   // C/D: row=(lane>>4)*4+m, col=lane&15
        pout[(size_t)row * OUTF + 0  + r] = acc0[m];
        pout[(size_t)row * OUTF + 16 + r] = acc1[m];
        pout[(size_t)row * OUTF + 32 + r] = acc2[m];
        pout[(size_t)row * OUTF + 48 + r] = acc3[m];
    }
}

// ---------------- Kernel 5: combine j-split partials + ELU ----------------
__global__ __launch_bounds__(256) void k5_combine(
    const float* __restrict__ part, float* __restrict__ out, int JS)
{
    const int idx = blockIdx.x * 256 + threadIdx.x;
    float v = 0.f;
    for (int s = 0; s < JS; ++s) v += part[(size_t)s * (NN * OUTF) + idx];
    out[idx] = v > 0.f ? v : (__builtin_amdgcn_exp2f(v * LOG2E) - 1.f);
}

extern "C" void kernel_launch(void* const* d_in, const int* in_sizes, int n_in,
                              void* d_out, int out_size, void* d_ws, size_t ws_size,
                              hipStream_t stream)
{
    const float* input  = (const float*)d_in[0];
    // d_in[1] = adj : unused by the reference computation
    const float* embeds = (const float*)d_in[2];
    const float* Wm     = (const float*)d_in[3];
    const float* av     = (const float*)d_in[4];
    const float* intw   = (const float*)d_in[5];
    // d_in[6] = intent_b : cancels in column softmax
    const float* betap  = (const float*)d_in[7];
    float* out = (float*)d_out;

    char* ws = (char*)d_ws;
    __hip_bfloat16* hT = (__hip_bfloat16*)(ws + OFF_HT);
    float* esL   = (float*)(ws + OFF_ES);
    float* edL   = (float*)(ws + OFF_ED);
    float* qL    = (float*)(ws + OFF_Q);
    float* mx    = (float*)(ws + OFF_MAX);
    float* Spart = (float*)(ws + OFF_SP);
    float* cc    = (float*)(ws + OFF_CC);
    float* part  = (float*)(ws + OFF_PART);

    // pick j-split for kernel 4 based on available workspace
    int JS = 4;
    while (JS > 1 &&
           (size_t)OFF_PART + (size_t)JS * NN * OUTF * sizeof(float) > ws_size)
        JS >>= 1;
    const int jchunk = NN / JS;

    k1_h<<<NN / 4, 256, 0, stream>>>(input, Wm, av, embeds, intw, betap,
                                     hT, esL, edL, qL);
    k1b_max<<<1, 256, 0, stream>>>(esL, qL, mx);
    k2_colsum<<<dim3(NN / 256, ISPLIT), 256, 0, stream>>>(esL, edL, qL, mx, Spart);
    k3_cc<<<NN / 256, 256, 0, stream>>>(edL, mx, Spart, cc);
    k4_mm<<<dim3(NN / 64, JS), 256, 0, stream>>>(esL, edL, qL, cc,
                                                 (const short*)hT, part, jchunk);
    k5_combine<<<(NN * OUTF) / 256, 256, 0, stream>>>(part, out, JS);
}

// Round 2
// 90.104 us; speedup vs baseline: 1.4547x; 1.4547x over previous
//
#include <hip/hip_runtime.h>
#include <hip/hip_bf16.h>

#define NN 8192
#define INF 128
#define OUTF 64
#define EMB 32
#define LOG2E 1.4426950408889634f
#define ISPLIT 32
#define ICH (NN / ISPLIT)
#define MGUARD 64.0f

typedef __attribute__((ext_vector_type(8))) short bf16x8;
typedef __attribute__((ext_vector_type(4))) float f32x4;

// workspace offsets (bytes)
#define OFF_HT   0u          // bf16 hT[64][8192]      : 1048576
#define OFF_UW   1048576u    // float2 uw[8192]        : 65536
#define OFF_E12  1114112u    // float2 e12[8192]       : 65536
#define OFF_SP   1179648u    // f32 Spart[32][8192]    : 1048576
#define OFF_PQ   2228224u    // float2 PQ[8192]        : 65536
#define OFF_PART 2293760u    // f32 part[JS][8192][64]

// ---------------- Kernel 1: h = input@W -> hT(bf16), uw=(u,w), e12=(e1,e2) ----------------
__global__ __launch_bounds__(256) void k1_h(
    const float* __restrict__ input, const float* __restrict__ Wm,
    const float* __restrict__ av, const float* __restrict__ embeds,
    const float* __restrict__ intw, const float* __restrict__ betap,
    __hip_bfloat16* __restrict__ hT, float2* __restrict__ uw,
    float2* __restrict__ e12)
{
    const int wid  = threadIdx.x >> 6;
    const int lane = threadIdx.x & 63;
    const int i = blockIdx.x * 4 + wid;

    const float a1 = av[lane];
    const float a2 = av[64 + lane];
    const float* xrow = input + (size_t)i * INF;

    float acc = 0.f;
#pragma unroll
    for (int k = 0; k < INF; k += 4) {
        float4 xv = *(const float4*)(xrow + k);
        acc = fmaf(xv.x, Wm[(k + 0) * OUTF + lane], acc);
        acc = fmaf(xv.y, Wm[(k + 1) * OUTF + lane], acc);
        acc = fmaf(xv.z, Wm[(k + 2) * OUTF + lane], acc);
        acc = fmaf(xv.w, Wm[(k + 3) * OUTF + lane], acc);
    }
    hT[(size_t)lane * NN + i] = __float2bfloat16(acc);

    float v1 = acc * a1;   // -> e_src_i
    float v2 = acc * a2;   // -> e_dst_i
#pragma unroll
    for (int o = 32; o > 0; o >>= 1) {
        v1 += __shfl_xor(v1, o);
        v2 += __shfl_xor(v2, o);
    }
    float p = 0.f;
    if (lane < EMB) p = embeds[(size_t)i * EMB + lane] * intw[lane];
#pragma unroll
    for (int o = 16; o > 0; o >>= 1) p += __shfl_xor(p, o);

    if (lane == 0) {
        const float q = betap[0] * p;
        uw[i]  = make_float2((v1 + q) * LOG2E, (0.2f * v1 + q) * LOG2E);
        e12[i] = make_float2(v2 * LOG2E, 0.2f * v2 * LOG2E);
    }
}

// ---------------- Kernel 2: partial column sums (exp2 domain, fixed anchor) ----------------
__global__ __launch_bounds__(256) void k2_colsum(
    const float2* __restrict__ uw, const float2* __restrict__ e12,
    float* __restrict__ Spart)
{
    const int j = blockIdx.x * 256 + threadIdx.x;
    const float2 e = e12[j];
    const float Mj = fmaxf(e.x, e.y) + MGUARD;
    const float A = e.x - Mj;
    const float B = e.y - Mj;

    const float* up = (const float*)uw + (size_t)blockIdx.y * ICH * 2;
    float s0 = 0.f, s1 = 0.f;
#pragma unroll 4
    for (int rr = 0; rr < ICH * 2; rr += 4) {
        float4 c = *(const float4*)(up + rr);     // u0,w0,u1,w1 (wave-uniform)
        s0 += __builtin_amdgcn_exp2f(fmaxf(c.x + A, c.y + B));
        s1 += __builtin_amdgcn_exp2f(fmaxf(c.z + A, c.w + B));
    }
    Spart[(size_t)blockIdx.y * NN + j] = s0 + s1;
}

// ---------------- Kernel 3: cc_j, then per-j constants PQ = e12 - cc ----------------
__global__ __launch_bounds__(256) void k3_cc(
    const float2* __restrict__ e12, const float* __restrict__ Spart,
    float2* __restrict__ PQ)
{
    const int j = blockIdx.x * 256 + threadIdx.x;
    float s = 0.f;
#pragma unroll
    for (int k = 0; k < ISPLIT; ++k) s += Spart[(size_t)k * NN + j];
    const float2 e = e12[j];
    const float Mj = fmaxf(e.x, e.y) + MGUARD;     // identical expr to k2 -> exact cancel
    const float cc = Mj + __builtin_amdgcn_logf(s);
    PQ[j] = make_float2(e.x - cc, e.y - cc);
}

// ---------------- Kernel 4: h_prime partial = attention @ h (MFMA bf16) ----------------
__global__ __launch_bounds__(256) void k4_mm(
    const float2* __restrict__ uw, const float2* __restrict__ PQ,
    const short* __restrict__ hTu, float* __restrict__ part, int jch)
{
    const int wid  = threadIdx.x >> 6;
    const int lane = threadIdx.x & 63;
    const int r = lane & 15;
    const int g = lane >> 4;
    const int ibase = blockIdx.x * 128 + wid * 32;

    const float2 c0 = uw[ibase + r];        // u,w for A-frag0 row
    const float2 c1 = uw[ibase + 16 + r];   // u,w for A-frag1 row

    const int jb = blockIdx.y * jch;
    const int je = jb + jch;

    f32x4 a00 = {0,0,0,0}, a01 = {0,0,0,0}, a02 = {0,0,0,0}, a03 = {0,0,0,0};
    f32x4 a10 = {0,0,0,0}, a11 = {0,0,0,0}, a12 = {0,0,0,0}, a13 = {0,0,0,0};

    for (int j0 = jb; j0 < je; j0 += 32) {
        const int jj = j0 + g * 8;
        const float* pqp = (const float*)(PQ + jj);
        const float4 q0 = *(const float4*)(pqp);       // P0 Q0 P1 Q1
        const float4 q1 = *(const float4*)(pqp + 4);
        const float4 q2 = *(const float4*)(pqp + 8);
        const float4 q3 = *(const float4*)(pqp + 12);

        float e00 = __builtin_amdgcn_exp2f(fmaxf(c0.x + q0.x, c0.y + q0.y));
        float e01 = __builtin_amdgcn_exp2f(fmaxf(c0.x + q0.z, c0.y + q0.w));
        float e02 = __builtin_amdgcn_exp2f(fmaxf(c0.x + q1.x, c0.y + q1.y));
        float e03 = __builtin_amdgcn_exp2f(fmaxf(c0.x + q1.z, c0.y + q1.w));
        float e04 = __builtin_amdgcn_exp2f(fmaxf(c0.x + q2.x, c0.y + q2.y));
        float e05 = __builtin_amdgcn_exp2f(fmaxf(c0.x + q2.z, c0.y + q2.w));
        float e06 = __builtin_amdgcn_exp2f(fmaxf(c0.x + q3.x, c0.y + q3.y));
        float e07 = __builtin_amdgcn_exp2f(fmaxf(c0.x + q3.z, c0.y + q3.w));

        float e10 = __builtin_amdgcn_exp2f(fmaxf(c1.x + q0.x, c1.y + q0.y));
        float e11 = __builtin_amdgcn_exp2f(fmaxf(c1.x + q0.z, c1.y + q0.w));
        float e12v= __builtin_amdgcn_exp2f(fmaxf(c1.x + q1.x, c1.y + q1.y));
        float e13 = __builtin_amdgcn_exp2f(fmaxf(c1.x + q1.z, c1.y + q1.w));
        float e14 = __builtin_amdgcn_exp2f(fmaxf(c1.x + q2.x, c1.y + q2.y));
        float e15 = __builtin_amdgcn_exp2f(fmaxf(c1.x + q2.z, c1.y + q2.w));
        float e16 = __builtin_amdgcn_exp2f(fmaxf(c1.x + q3.x, c1.y + q3.y));
        float e17 = __builtin_amdgcn_exp2f(fmaxf(c1.x + q3.z, c1.y + q3.w));

        union { bf16x8 v; unsigned u[4]; } A0, A1;
        asm("v_cvt_pk_bf16_f32 %0, %1, %2" : "=v"(A0.u[0]) : "v"(e00), "v"(e01));
        asm("v_cvt_pk_bf16_f32 %0, %1, %2" : "=v"(A0.u[1]) : "v"(e02), "v"(e03));
        asm("v_cvt_pk_bf16_f32 %0, %1, %2" : "=v"(A0.u[2]) : "v"(e04), "v"(e05));
        asm("v_cvt_pk_bf16_f32 %0, %1, %2" : "=v"(A0.u[3]) : "v"(e06), "v"(e07));
        asm("v_cvt_pk_bf16_f32 %0, %1, %2" : "=v"(A1.u[0]) : "v"(e10), "v"(e11));
        asm("v_cvt_pk_bf16_f32 %0, %1, %2" : "=v"(A1.u[1]) : "v"(e12v),"v"(e13));
        asm("v_cvt_pk_bf16_f32 %0, %1, %2" : "=v"(A1.u[2]) : "v"(e14), "v"(e15));
        asm("v_cvt_pk_bf16_f32 %0, %1, %2" : "=v"(A1.u[3]) : "v"(e16), "v"(e17));

        const bf16x8 b0 = *(const bf16x8*)(hTu + (size_t)(0  + r) * NN + jj);
        const bf16x8 b1 = *(const bf16x8*)(hTu + (size_t)(16 + r) * NN + jj);
        const bf16x8 b2 = *(const bf16x8*)(hTu + (size_t)(32 + r) * NN + jj);
        const bf16x8 b3 = *(const bf16x8*)(hTu + (size_t)(48 + r) * NN + jj);

        a00 = __builtin_amdgcn_mfma_f32_16x16x32_bf16(A0.v, b0, a00, 0, 0, 0);
        a01 = __builtin_amdgcn_mfma_f32_16x16x32_bf16(A0.v, b1, a01, 0, 0, 0);
        a02 = __builtin_amdgcn_mfma_f32_16x16x32_bf16(A0.v, b2, a02, 0, 0, 0);
        a03 = __builtin_amdgcn_mfma_f32_16x16x32_bf16(A0.v, b3, a03, 0, 0, 0);
        a10 = __builtin_amdgcn_mfma_f32_16x16x32_bf16(A1.v, b0, a10, 0, 0, 0);
        a11 = __builtin_amdgcn_mfma_f32_16x16x32_bf16(A1.v, b1, a11, 0, 0, 0);
        a12 = __builtin_amdgcn_mfma_f32_16x16x32_bf16(A1.v, b2, a12, 0, 0, 0);
        a13 = __builtin_amdgcn_mfma_f32_16x16x32_bf16(A1.v, b3, a13, 0, 0, 0);
    }

    float* pout = part + (size_t)blockIdx.y * (NN * OUTF);
#pragma unroll
    for (int m = 0; m < 4; ++m) {
        const int row0 = ibase + g * 4 + m;
        const int row1 = ibase + 16 + g * 4 + m;
        pout[(size_t)row0 * OUTF + 0  + r] = a00[m];
        pout[(size_t)row0 * OUTF + 16 + r] = a01[m];
        pout[(size_t)row0 * OUTF + 32 + r] = a02[m];
        pout[(size_t)row0 * OUTF + 48 + r] = a03[m];
        pout[(size_t)row1 * OUTF + 0  + r] = a10[m];
        pout[(size_t)row1 * OUTF + 16 + r] = a11[m];
        pout[(size_t)row1 * OUTF + 32 + r] = a12[m];
        pout[(size_t)row1 * OUTF + 48 + r] = a13[m];
    }
}

// ---------------- Kernel 5: combine j-split partials + ELU (float4) ----------------
__global__ __launch_bounds__(256) void k5_combine(
    const float* __restrict__ part, float* __restrict__ out, int JS)
{
    const int base = (blockIdx.x * 256 + threadIdx.x) * 4;
    float4 v = make_float4(0.f, 0.f, 0.f, 0.f);
    for (int s = 0; s < JS; ++s) {
        const float4 p = *(const float4*)(part + (size_t)s * (NN * OUTF) + base);
        v.x += p.x; v.y += p.y; v.z += p.z; v.w += p.w;
    }
    float4 o;
    o.x = v.x > 0.f ? v.x : (__builtin_amdgcn_exp2f(v.x * LOG2E) - 1.f);
    o.y = v.y > 0.f ? v.y : (__builtin_amdgcn_exp2f(v.y * LOG2E) - 1.f);
    o.z = v.z > 0.f ? v.z : (__builtin_amdgcn_exp2f(v.z * LOG2E) - 1.f);
    o.w = v.w > 0.f ? v.w : (__builtin_amdgcn_exp2f(v.w * LOG2E) - 1.f);
    *(float4*)(out + base) = o;
}

extern "C" void kernel_launch(void* const* d_in, const int* in_sizes, int n_in,
                              void* d_out, int out_size, void* d_ws, size_t ws_size,
                              hipStream_t stream)
{
    const float* input  = (const float*)d_in[0];
    // d_in[1] = adj : unused by the reference computation
    const float* embeds = (const float*)d_in[2];
    const float* Wm     = (const float*)d_in[3];
    const float* av     = (const float*)d_in[4];
    const float* intw   = (const float*)d_in[5];
    // d_in[6] = intent_b : cancels in column softmax
    const float* betap  = (const float*)d_in[7];
    float* out = (float*)d_out;

    char* ws = (char*)d_ws;
    __hip_bfloat16* hT = (__hip_bfloat16*)(ws + OFF_HT);
    float2* uw   = (float2*)(ws + OFF_UW);
    float2* e12  = (float2*)(ws + OFF_E12);
    float* Spart = (float*)(ws + OFF_SP);
    float2* PQ   = (float2*)(ws + OFF_PQ);
    float* part  = (float*)(ws + OFF_PART);

    int JS = 8;
    while (JS > 1 &&
           (size_t)OFF_PART + (size_t)JS * NN * OUTF * sizeof(float) > ws_size)
        JS >>= 1;
    const int jch = NN / JS;

    k1_h<<<NN / 4, 256, 0, stream>>>(input, Wm, av, embeds, intw, betap,
                                     hT, uw, e12);
    k2_colsum<<<dim3(NN / 256, ISPLIT), 256, 0, stream>>>(uw, e12, Spart);
    k3_cc<<<NN / 256, 256, 0, stream>>>(e12, Spart, PQ);
    k4_mm<<<dim3(NN / 128, JS), 256, 0, stream>>>(uw, PQ, (const short*)hT,
                                                  part, jch);
    k5_combine<<<(NN * OUTF) / 1024, 256, 0, stream>>>(part, out, JS);
}